// Round 7
// baseline (459.653 us; speedup 1.0000x reference)
//
#include <hip/hip_runtime.h>
#include <cmath>

#define MP1 524288
#define NXP 32768

typedef float vfloat4 __attribute__((ext_vector_type(4)));
typedef float vfloat2 __attribute__((ext_vector_type(2)));

// ws layout (float offsets):
//   [0,4096)        gemv partials [row*32+chunk]
//   [8192,24576)    WT2t[k*128+j] = Wt2[j*128+k]
//   [24576,28672)   WE2t[i*64+m]  = We2[m*64+i]
//   [28672,45056)   WT3t[k*128+j] = Wt3[j*128+k]
#define PART_   0
#define WT2T_   8192
#define WE2T_   24576
#define WT3T_   28672

// tanh via native exp2 + rcp: 6 VALU ops vs ~20 for libm tanhf.
__device__ __forceinline__ float tanh_fast(float x) {
    x = fminf(20.f, fmaxf(-20.f, x));
    float t = exp2f(x * 2.8853900817779268f);       // e^(2x)
    return (t - 1.f) * __builtin_amdgcn_rcpf(t + 1.f);
}

// gemv (~45us, near the 43us HBM floor for the 268MB Wb stream) + tail blocks
// (y>=32) doing the three weight transposes concurrently with the stream.
__global__ __launch_bounds__(256) void gemv_k(const float* __restrict__ Wb,
                                              const float* __restrict__ a,
                                              const float* __restrict__ Wt2,
                                              const float* __restrict__ We2,
                                              const float* __restrict__ Wt3,
                                              float* __restrict__ ws) {
    const int y = blockIdx.y;
    const int tid = threadIdx.x;
    if (y >= 32) {                       // transpose tail
        int idx = blockIdx.x * 256 + tid;
        if (y == 32) {
            if (idx < 16384) {
                int j = idx >> 7, k = idx & 127;
                ws[WT2T_ + k * 128 + j] = Wt2[idx];
            } else if (idx < 20480) {
                int e = idx - 16384;
                int m = e >> 6, i2 = e & 63;
                ws[WE2T_ + i2 * 64 + m] = We2[e];
            }
        } else {
            if (idx < 16384) {
                int j = idx >> 7, k = idx & 127;
                ws[WT3T_ + k * 128 + j] = Wt3[idx];
            }
        }
        return;
    }
    const int row = blockIdx.x;
    const int chunk = y;
    size_t base = (size_t)row * MP1 + (size_t)chunk * 16384;
    const vfloat4* W4 = (const vfloat4*)(Wb + base);
    const float4* A4 = (const float4*)(a + (size_t)chunk * 16384);
    float sum = 0.0f;
#pragma unroll
    for (int it = 0; it < 16; ++it) {
        vfloat4 w = __builtin_nontemporal_load(&W4[tid + it * 256]);
        float4 av = A4[tid + it * 256];
        sum += w[0] * av.x + w[1] * av.y + w[2] * av.z + w[3] * av.w;
    }
#pragma unroll
    for (int off = 32; off > 0; off >>= 1) sum += __shfl_down(sum, off, 64);
    __shared__ float red[4];
    int wid = tid >> 6;
    if ((tid & 63) == 0) red[wid] = sum;
    __syncthreads();
    if (tid == 0) ws[PART_ + row * 32 + chunk] = red[0] + red[1] + red[2] + red[3];
}

// point_k: VALU-issue-bound (R4: VALUBusy 90.6%). R7: the accumulation loops
// now use vfloat2 + __builtin_elementwise_fma so the backend can emit
// v_pk_fma_f32 (VOP3P, 2 FMA/inst — the only path to the 157 TF fp32 rate).
// Halves the dominant FMA instruction stream: B 64->32/k, C 72->36/ii.
// Numerically identical: IEEE fma per component, same accumulation order.
// LDS (floats):
#define SW_WT1 0        // 256: Wt1 interleaved [k][2]
#define SW_BT1 256      // 128
#define SW_BT2 384      // 128
#define SW_CVEC 512     // 128 (computed in-block)
#define SW_WE1X 640     // 512: per-ii {w0,w1,w00,w01,w11,w00w1,w01w1,w11w1}
#define SW_BE1 1152     // 64
#define SW_BE2 1216     // 64
#define SW_WE3 1280     // 64
#define SW_B 1344       // 128: b = bb + sum(partials)
#define WTAB 1472       // 512: per-k {w, w^2, w^3, 0}
#define REDU 1984       // 16: u_const partial sums
#define UREDP 2000      // 256: reduced u jets, plane-major [r*64+p]
#define H1V_ 2256       // 8192: trunk h1 [k*64+p]; phase C reuses [0,4096)
#define FREDP (H1V_ + 4096)   // 3072: F partial planes
#define SCR_ 10448      // 8192: Wt2t 64-k chunk (B) -> RED planes -> We2t (C)
#define LDSF 18640      // 74,560 B -> 2 blocks/CU

__global__ __launch_bounds__(512, 4) void point_k(const float* __restrict__ x,
                                                  const float* __restrict__ tptr,
                                                  const float* __restrict__ Wt1,
                                                  const float* __restrict__ bt1,
                                                  const float* __restrict__ bt2,
                                                  const float* __restrict__ We1,
                                                  const float* __restrict__ be1,
                                                  const float* __restrict__ be2,
                                                  const float* __restrict__ We3,
                                                  const float* __restrict__ bb,
                                                  const float* __restrict__ bt3,
                                                  const float* __restrict__ ws,
                                                  float* __restrict__ out) {
    __shared__ __align__(16) float lds[LDSF];
    const int tid = threadIdx.x;
    const int p = tid & 63;
    const int slice = __builtin_amdgcn_readfirstlane(tid >> 6);
    const int i = blockIdx.x * 64 + p;
    const float xi = x[i];
    const float tt = tptr[0];
    const vfloat2 ZV = {0.f, 0.f};

    // ---- stage small weights, w-power tables, and b = bb + sum(partials) ----
    if (tid < 256) lds[SW_WT1 + tid] = Wt1[tid];
    else if (tid < 384) lds[SW_BT1 + tid - 256] = bt1[tid - 256];
    else lds[SW_BT2 + tid - 384] = bt2[tid - 384];
    if (tid < 128) {
        float w0 = Wt1[2 * tid];
        float* T = lds + WTAB + tid * 4;
        T[0] = w0; T[1] = w0 * w0; T[2] = w0 * w0 * w0; T[3] = 0.f;
    } else if (tid < 192) lds[SW_BE1 + tid - 128] = be1[tid - 128];
    else if (tid < 256) lds[SW_BE2 + tid - 192] = be2[tid - 192];
    else if (tid < 320) lds[SW_WE3 + tid - 256] = We3[tid - 256];
    else if (tid < 384) {
        int ii = tid - 320;
        float w0 = We1[2 * ii], w1 = We1[2 * ii + 1];
        float w00 = w0 * w0, w01 = w0 * w1, w11 = w1 * w1;
        float* X = lds + SW_WE1X + ii * 8;
        X[0] = w0; X[1] = w1; X[2] = w00; X[3] = w01; X[4] = w11;
        X[5] = w00 * w1; X[6] = w01 * w1; X[7] = w11 * w1;
    } else {
        int j = tid - 384;                       // 0..127
        const float4* P4 = (const float4*)(ws + PART_ + j * 32);
        float b = bb[j];
#pragma unroll
        for (int q = 0; q < 8; ++q) {
            float4 v4 = P4[q];
            b += v4.x; b += v4.y; b += v4.z; b += v4.w;
        }
        lds[SW_B + j] = b;
    }
    __syncthreads();

    // ---- Phase A: trunk layer-1 tanh values (16 k's per thread) ----
#pragma unroll
    for (int q = 0; q < 16; ++q) {
        int k = slice * 16 + q;
        float z = fmaf(lds[SW_WT1 + 2 * k], xi,
                       fmaf(lds[SW_WT1 + 2 * k + 1], tt, lds[SW_BT1 + k]));
        lds[H1V_ + k * 64 + p] = tanh_fast(z);
    }
    // ---- cvec + u_const (threads 0..127, overlapped with phase A of others) ----
    if (tid < 128) {
        float cv = 0.f;
        const float4* W4 = (const float4*)(ws + WT3T_ + tid * 128);
#pragma unroll 4
        for (int q = 0; q < 32; ++q) {
            float4 wv = W4[q];
            cv = fmaf(lds[SW_B + 4 * q + 0], wv.x, cv);
            cv = fmaf(lds[SW_B + 4 * q + 1], wv.y, cv);
            cv = fmaf(lds[SW_B + 4 * q + 2], wv.z, cv);
            cv = fmaf(lds[SW_B + 4 * q + 3], wv.w, cv);
        }
        lds[SW_CVEC + tid] = cv;
        float pk_ = lds[SW_B + tid] * bt3[tid];
#pragma unroll
        for (int off = 32; off > 0; off >>= 1) pk_ += __shfl_down(pk_, off, 64);
        if ((tid & 63) == 0) lds[REDU + (tid >> 6)] = pk_;
    }

    // ---- Phase B: trunk layer-2 jets; Wt2^T streamed in 2x(8192 float) chunks.
    // Packed accumulators (vfloat2): a2' = v*s*w^2 (d2 = -2a2'),
    // a3' = s*(2-3s)*w^3 (d3 = 2a3'); constants folded into the finalize.
    vfloat2 a0v[8], a1v[8], a2v[8], a3v[8];
#pragma unroll
    for (int q = 0; q < 8; ++q) { a0v[q] = ZV; a1v[q] = ZV; a2v[q] = ZV; a3v[q] = ZV; }
    for (int c = 0; c < 2; ++c) {
        __syncthreads();   // c=0: staging+phaseA+cvec done; c=1: prev sweep done
        {
            const float4* src = (const float4*)(ws + WT2T_ + c * 8192);
            float4* dst = (float4*)(lds + SCR_);
            dst[tid] = src[tid];
            dst[tid + 512] = src[tid + 512];
            dst[tid + 1024] = src[tid + 1024];
            dst[tid + 1536] = src[tid + 1536];
        }
        __syncthreads();
#pragma unroll 1
        for (int kl = 0; kl < 64; ++kl) {
            int k = c * 64 + kl;
            float v = lds[H1V_ + k * 64 + p];
            const vfloat4* wtp = (const vfloat4*)(lds + WTAB + k * 4);  // uniform
            vfloat4 wt = wtp[0];                 // {w, w^2, w^3, 0}
            float s = fmaf(-v, v, 1.f);
            float t2 = v * s;                    // f2 = -2*t2
            float m = fmaf(-3.f, s, 2.f);        // 2v^2-s == 2-3s
            float sm = s * m;                    // f3 = 2*sm
            float d1 = s * wt.x;
            float d2 = t2 * wt.y;
            float d3 = sm * wt.z;
            vfloat2 vv = {v, v}, d1v = {d1, d1}, d2v = {d2, d2}, d3v = {d3, d3};
            const vfloat4* wr = (const vfloat4*)(lds + SCR_ + kl * 128 + slice * 16);
            vfloat4 wv0 = wr[0], wv1 = wr[1], wv2 = wr[2], wv3 = wr[3];
            const vfloat2 wp[8] = {wv0.xy, wv0.zw, wv1.xy, wv1.zw,
                                   wv2.xy, wv2.zw, wv3.xy, wv3.zw};
#pragma unroll
            for (int q = 0; q < 8; ++q) {
                vfloat2 w2 = wp[q];
                a0v[q] = __builtin_elementwise_fma(w2, vv,  a0v[q]);
                a1v[q] = __builtin_elementwise_fma(w2, d1v, a1v[q]);
                a2v[q] = __builtin_elementwise_fma(w2, d2v, a2v[q]);
                a3v[q] = __builtin_elementwise_fma(w2, d3v, a3v[q]);
            }
        }
    }
    // finalize this slice's u-jet partials (scale fixups applied here)
    float u0 = 0.f, u1 = 0.f, u2 = 0.f, u3 = 0.f;
#pragma unroll
    for (int jj = 0; jj < 16; ++jj) {
        int j = slice * 16 + jj;
        float z0 = a0v[jj >> 1][jj & 1] + lds[SW_BT2 + j];
        float z1 = a1v[jj >> 1][jj & 1];
        float z2 = -2.f * a2v[jj >> 1][jj & 1];
        float z3 = 2.f * a3v[jj >> 1][jj & 1];
        float v = tanh_fast(z0);
        float s = 1.f - v * v;
        float f2 = -2.f * v * s;
        float f3 = 2.f * s * (2.f * v * v - s);
        float cj = lds[SW_CVEC + j];
        u0 = fmaf(cj, v, u0);
        u1 = fmaf(cj, s * z1, u1);
        u2 = fmaf(cj, f2 * z1 * z1 + s * z2, u2);
        u3 = fmaf(cj, f3 * z1 * z1 * z1 + 3.f * f2 * z1 * z2 + s * z3, u3);
    }
    __syncthreads();   // sweeps done -> SCR_ reusable as RED planes
    lds[SCR_ + 0 * 512 + slice * 64 + p] = u0;   // plane-major: conflict-free
    lds[SCR_ + 1 * 512 + slice * 64 + p] = u1;
    lds[SCR_ + 2 * 512 + slice * 64 + p] = u2;
    lds[SCR_ + 3 * 512 + slice * 64 + p] = u3;
    __syncthreads();

    // ---- reduce u jets across slices (threads 0..63) ----
    if (tid < 64) {
        float r0 = lds[REDU] + lds[REDU + 1];    // u_const
        float r1 = 0.f, r2 = 0.f, r3 = 0.f;
#pragma unroll
        for (int s = 0; s < 8; ++s) {
            r0 += lds[SCR_ + 0 * 512 + s * 64 + tid];
            r1 += lds[SCR_ + 1 * 512 + s * 64 + tid];
            r2 += lds[SCR_ + 2 * 512 + s * 64 + tid];
            r3 += lds[SCR_ + 3 * 512 + s * 64 + tid];
        }
        lds[UREDP + 0 * 64 + tid] = r0;
        lds[UREDP + 1 * 64 + tid] = r1;
        lds[UREDP + 2 * 64 + tid] = r2;
        lds[UREDP + 3 * 64 + tid] = r3;
    }
    __syncthreads();   // RED consumed -> SCR_ reusable for We2t

    // ---- Phase C part 1: stage We2t + energy layer-1 tanh values ----
    {
        const float4* src = (const float4*)(ws + WE2T_);
        float4* dst = (float4*)(lds + SCR_);
        dst[tid] = src[tid];
        dst[tid + 512] = src[tid + 512];
    }
    const float y = lds[UREDP + 0 * 64 + p];
    const float z = lds[UREDP + 1 * 64 + p];
#pragma unroll
    for (int q = 0; q < 8; ++q) {
        int ii = slice * 8 + q;
        float g = fmaf(lds[SW_WE1X + ii * 8], y,
                       fmaf(lds[SW_WE1X + ii * 8 + 1], z, lds[SW_BE1 + ii]));
        lds[H1V_ + ii * 64 + p] = tanh_fast(g);
    }
    __syncthreads();

    // ---- Phase C part 2: energy layer-2 jets (packed, scaled accumulators:
    // A3..A5 hold (v*s)*wprod -> true G = -2A; A6..A8 hold (s*(2-3s))*wprod
    // -> true = 2A; fixups at finalize) ----
    {
        vfloat2 A0v[4], A1v[4], A2v[4], A3v[4], A4v[4], A5v[4], A6v[4], A7v[4], A8v[4];
#pragma unroll
        for (int q = 0; q < 4; ++q) {
            A0v[q] = ZV; A1v[q] = ZV; A2v[q] = ZV; A3v[q] = ZV; A4v[q] = ZV;
            A5v[q] = ZV; A6v[q] = ZV; A7v[q] = ZV; A8v[q] = ZV;
        }
#pragma unroll 1
        for (int ii = 0; ii < 64; ++ii) {
            float v = lds[H1V_ + ii * 64 + p];
            const vfloat4* xw = (const vfloat4*)(lds + SW_WE1X + ii * 8);  // uniform
            vfloat4 xa = xw[0], xb = xw[1];
            float s = fmaf(-v, v, 1.f);
            float t2 = v * s;
            float m = fmaf(-3.f, s, 2.f);
            float sm = s * m;
            float j1 = s * xa.x, j2 = s * xa.y;
            float j3 = t2 * xa.z, j4 = t2 * xa.w, j5 = t2 * xb.x;
            float j6 = sm * xb.y, j7 = sm * xb.z, j8 = sm * xb.w;
            vfloat2 vv = {v, v};
            vfloat2 j1v = {j1, j1}, j2v = {j2, j2}, j3v = {j3, j3}, j4v = {j4, j4};
            vfloat2 j5v = {j5, j5}, j6v = {j6, j6}, j7v = {j7, j7}, j8v = {j8, j8};
            const vfloat4* wr = (const vfloat4*)(lds + SCR_ + ii * 64 + slice * 8);
            vfloat4 wv0 = wr[0], wv1 = wr[1];
            const vfloat2 wp[4] = {wv0.xy, wv0.zw, wv1.xy, wv1.zw};
#pragma unroll
            for (int q = 0; q < 4; ++q) {
                vfloat2 w2 = wp[q];
                A0v[q] = __builtin_elementwise_fma(w2, vv,  A0v[q]);
                A1v[q] = __builtin_elementwise_fma(w2, j1v, A1v[q]);
                A2v[q] = __builtin_elementwise_fma(w2, j2v, A2v[q]);
                A3v[q] = __builtin_elementwise_fma(w2, j3v, A3v[q]);
                A4v[q] = __builtin_elementwise_fma(w2, j4v, A4v[q]);
                A5v[q] = __builtin_elementwise_fma(w2, j5v, A5v[q]);
                A6v[q] = __builtin_elementwise_fma(w2, j6v, A6v[q]);
                A7v[q] = __builtin_elementwise_fma(w2, j7v, A7v[q]);
                A8v[q] = __builtin_elementwise_fma(w2, j8v, A8v[q]);
            }
        }
        float Fyy = 0.f, Fyz = 0.f, Fzz = 0.f, Fyyz = 0.f, Fyzz = 0.f, Fzzz = 0.f;
#pragma unroll
        for (int mm = 0; mm < 8; ++mm) {
            int m = slice * 8 + mm;
            int qh = mm >> 1, ql = mm & 1;
            float G0 = A0v[qh][ql] + lds[SW_BE2 + m];
            float v = tanh_fast(G0);
            float s = 1.f - v * v;
            float f2 = -2.f * v * s;
            float f3 = 2.f * s * (2.f * v * v - s);
            float Gy = A1v[qh][ql], Gz = A2v[qh][ql];
            float Gyy = -2.f * A3v[qh][ql], Gyz = -2.f * A4v[qh][ql], Gzz = -2.f * A5v[qh][ql];
            float Gyyz = 2.f * A6v[qh][ql], Gyzz = 2.f * A7v[qh][ql], Gzzz = 2.f * A8v[qh][ql];
            float Hyy = f2 * Gy * Gy + s * Gyy;
            float Hyz = f2 * Gy * Gz + s * Gyz;
            float Hzz = f2 * Gz * Gz + s * Gzz;
            float Hyyz = f3 * Gy * Gy * Gz + f2 * (Gyy * Gz + 2.f * Gyz * Gy) + s * Gyyz;
            float Hyzz = f3 * Gy * Gz * Gz + f2 * (2.f * Gyz * Gz + Gzz * Gy) + s * Gyzz;
            float Hzzz = f3 * Gz * Gz * Gz + 3.f * f2 * Gzz * Gz + s * Gzzz;
            float w3 = lds[SW_WE3 + m];
            Fyy  = fmaf(w3, Hyy,  Fyy);
            Fyz  = fmaf(w3, Hyz,  Fyz);
            Fzz  = fmaf(w3, Hzz,  Fzz);
            Fyyz = fmaf(w3, Hyyz, Fyyz);
            Fyzz = fmaf(w3, Hyzz, Fyzz);
            Fzzz = fmaf(w3, Hzzz, Fzzz);
        }
        lds[FREDP + 0 * 512 + slice * 64 + p] = Fyy;   // plane-major
        lds[FREDP + 1 * 512 + slice * 64 + p] = Fyz;
        lds[FREDP + 2 * 512 + slice * 64 + p] = Fzz;
        lds[FREDP + 3 * 512 + slice * 64 + p] = Fyyz;
        lds[FREDP + 4 * 512 + slice * 64 + p] = Fyzz;
        lds[FREDP + 5 * 512 + slice * 64 + p] = Fzzz;
    }
    __syncthreads();

    // ---- reduce F partials + combine (threads 0..63) ----
    if (tid < 64) {
        float F[6] = {0.f, 0.f, 0.f, 0.f, 0.f, 0.f};
#pragma unroll
        for (int s = 0; s < 8; ++s) {
#pragma unroll
            for (int q = 0; q < 6; ++q) F[q] += lds[FREDP + q * 512 + s * 64 + tid];
        }
        float u1r = lds[UREDP + 1 * 64 + tid];
        float u2r = lds[UREDP + 2 * 64 + tid];
        float u3r = lds[UREDP + 3 * 64 + tid];
        float F_yx  = F[0] * u1r + F[1] * u2r;
        float F_zxx = F[1] * u2r + F[2] * u3r + F[3] * u1r * u1r
                    + 2.f * F[4] * u1r * u2r + F[5] * u2r * u2r;
        out[blockIdx.x * 64 + tid] = F_zxx - F_yx;
    }
}

extern "C" void kernel_launch(void* const* d_in, const int* in_sizes, int n_in,
                              void* d_out, int out_size, void* d_ws, size_t ws_size,
                              hipStream_t stream) {
    const float* a   = (const float*)d_in[0];
    const float* x   = (const float*)d_in[1];
    const float* t   = (const float*)d_in[2];
    const float* Wb  = (const float*)d_in[3];
    const float* bb  = (const float*)d_in[4];
    const float* Wt1 = (const float*)d_in[5];
    const float* bt1 = (const float*)d_in[6];
    const float* Wt2 = (const float*)d_in[7];
    const float* bt2 = (const float*)d_in[8];
    const float* Wt3 = (const float*)d_in[9];
    const float* bt3 = (const float*)d_in[10];
    const float* We1 = (const float*)d_in[11];
    const float* be1 = (const float*)d_in[12];
    const float* We2 = (const float*)d_in[13];
    const float* be2 = (const float*)d_in[14];
    const float* We3 = (const float*)d_in[15];

    float* ws = (float*)d_ws;
    float* out = (float*)d_out;

    // 2 launches: gemv (+transpose tail blocks y>=32) -> point (inlined prep).
    gemv_k<<<dim3(128, 34), 256, 0, stream>>>(Wb, a, Wt2, We2, Wt3, ws);
    point_k<<<NXP / 64, 512, 0, stream>>>(x, t, Wt1, bt1, bt2, We1, be1, be2, We3,
                                          bb, bt3, ws, out);
}